// Round 6
// baseline (74.958 us; speedup 1.0000x reference)
//
#include <hip/hip_runtime.h>
#include <math.h>

#define B_ 32
#define N_ 2048
#define M_ 16
#define K_ 32
#define EPS 1e-12f

constexpr int NC      = 512;           // rows per chunk (R5: 128 -> 512; 4x fewer blocks)
constexpr int NCHUNK  = N_ / NC;       // 4
constexpr int THREADS = 512;           // thread = (k 0..31) x (grp 0..15); 32 rows/thread
constexpr int NWAVE   = THREADS / 64;  // 8
constexpr int YSTRIDE = 20;            // padded row stride: 80 B, 16B-aligned, non-pow2
constexpr int F4      = NC * (M_ + 1) / 4;  // 2176 float4 per chunk
constexpr int SLICE64 = K_ * M_ / 2;   // 256 packed u64 per (b,c) slice
constexpr unsigned FLAG_TAG = 0xA5B1u; // high-16 marker (poison != TAG, validated R3-R5)

// fast atanh: 0.5*ln((1+x)/(1-x)); x in [0, 1-1e-5] -> rcp arg >= 1e-5, safe.
__device__ __forceinline__ float fast_atanh(float x) {
    float ratio = (1.0f + x) * __builtin_amdgcn_rcpf(1.0f - x);
    return 0.34657359f * __log2f(ratio);
}

// ------------- single-dispatch fused kernel, ZERO-WAIT election handshake -------------
// R5 analysis: handshake (131K u64 exchanges + 8K flag RMWs + per-block far-atomic
// round-trips + 16-slice winner tail) dominated the ~23 us kernel; compute is ~2-4 us
// at any width >= 128 blocks. This round: 4x fewer blocks (128 x 512 thr), identical
// election protocol -> 4x less handshake on every axis.
// Protocol per block (c,b):
//   1. compute chunk partial (rows < chunk-local first-invalid; masked rows are
//      all-zero -> invalid -> trailing chunks do zero iterations),
//   2. publish the 512-float slice as 256 u64 atomic exchanges (coherent point,
//      overwrites poison),
//   3. vmcnt(0)+barrier, then exchange done[b][c] = TAG|local_mn, vmcnt(0),
//   4. read the batch's 4 done flags ONCE (RMW) - no spinning. Not all set -> exit.
//      All set -> one-shot election on elect[b]; the unique winner sums slices and
//      runs the epilogue. The chronologically-last publisher sees all 4 flags (its
//      reads issue after its own ack, which follows everyone else's ack at the
//      coherent point) -> exactly one winner. No co-residency assumption (G16-clean).
__global__ __launch_bounds__(THREADS) void pml_fused_kernel(
    const float* __restrict__ dgm, const float* __restrict__ theta,
    const float* __restrict__ class_w,
    unsigned long long* __restrict__ G_part,   // [B][NCHUNK][SLICE64]
    unsigned* __restrict__ done,               // [B][NCHUNK]
    unsigned* __restrict__ elect,              // [B]
    float* __restrict__ out)
{
    __shared__ __align__(16) float y_lds[NC * YSTRIDE];  // 40 KB
    __shared__ float hom_lds[NC];                        // 2 KB
    __shared__ float w_lds[NC];                          // 2 KB
    __shared__ unsigned wred[NWAVE];
    __shared__ float red[NWAVE][K_ * (M_ + 1)];          // 17 KB, stride-17
    __shared__ float S_lds[K_ * M_];                     // 2 KB (winner only)
    __shared__ unsigned fl_lds[NCHUNK];
    __shared__ int win;

    const int b    = blockIdx.y;
    const int c    = blockIdx.x;
    const int tid  = threadIdx.x;
    const int k    = tid & (K_ - 1);
    const int grp  = tid >> 5;        // 0..15
    const int lane = tid & 63;
    const int wv   = tid >> 6;        // 0..7

    // ---- stage chunk: 8704 contiguous floats = 2176 float4 (16B-aligned:
    // chunk offset = 512*17*4 B = 34816 B, base = b*2048*17*4 B, both /16) ----
    const float4* src4 = (const float4*)(dgm + ((size_t)b * N_ + c * NC) * (M_ + 1));
    for (int i4 = tid; i4 < F4; i4 += THREADS) {
        float4 v = src4[i4];
        int i  = i4 * 4;
        int nl = i / (M_ + 1);
        int j  = i - nl * (M_ + 1);
        float vv[4] = { v.x, v.y, v.z, v.w };
#pragma unroll
        for (int e = 0; e < 4; ++e) {
            if (j == 0) hom_lds[nl] = vv[e];
            else        y_lds[nl * YSTRIDE + (j - 1)] = vv[e];
            if (++j == M_ + 1) { j = 0; ++nl; }
        }
    }
    __syncthreads();

    // ---- local validity scan: 512 threads, one row each (all 8 waves full) ----
    const float cw0 = class_w[0], cw1 = class_w[1];
    {
        const float4* yv = (const float4*)(y_lds + tid * YSTRIDE);
        float4 a0 = yv[0], a1 = yv[1], a2 = yv[2], a3 = yv[3];
        float  h  = hom_lds[tid];
        bool nz = (h != 0.0f) |
                  (a0.x != 0.0f) | (a0.y != 0.0f) | (a0.z != 0.0f) | (a0.w != 0.0f) |
                  (a1.x != 0.0f) | (a1.y != 0.0f) | (a1.z != 0.0f) | (a1.w != 0.0f) |
                  (a2.x != 0.0f) | (a2.y != 0.0f) | (a2.z != 0.0f) | (a2.w != 0.0f) |
                  (a3.x != 0.0f) | (a3.y != 0.0f) | (a3.z != 0.0f) | (a3.w != 0.0f);
        bool ok = ((int)h <= 1) && nz;
        unsigned long long bal = __ballot(!ok);
        if (lane == 0)
            wred[wv] = bal ? (unsigned)(wv * 64 + (__ffsll((long long)bal) - 1))
                           : 0xFFFFFFFFu;
        int hc = min(max((int)h, 0), 1);
        w_lds[tid] = hc ? cw1 : cw0;
    }
    __syncthreads();
    unsigned mn_u = (unsigned)NC;
#pragma unroll
    for (int w = 0; w < NWAVE; ++w) mn_u = min(mn_u, wred[w]);
    const int local_mn = (int)mn_u;

    // ---- per-thread accumulation over rows grp, grp+16, ... < local_mn ----
    float t2[M_];
#pragma unroll
    for (int m = 0; m < M_; ++m) { float t = theta[k * M_ + m]; t2[m] = t * t; }
    float g[M_];
#pragma unroll
    for (int m = 0; m < M_; ++m) g[m] = 0.0f;

    for (int nl = grp; nl < local_mn; nl += 16) {
        float w = w_lds[nl];                                       // broadcast
        const float4* yv = (const float4*)(y_lds + nl * YSTRIDE);  // broadcast
        float4 a0 = yv[0], a1 = yv[1], a2 = yv[2], a3 = yv[3];
        float y[M_] = { a0.x, a0.y, a0.z, a0.w,  a1.x, a1.y, a1.z, a1.w,
                        a2.x, a2.y, a2.z, a2.w,  a3.x, a3.y, a3.z, a3.w };
        float s = 0.0f;
#pragma unroll
        for (int m = 0; m < M_; ++m) s = fmaf(y[m] * y[m], t2[m], s);
        float d   = 1.0f + sqrtf(1.0f + s + EPS);
        float rd  = __builtin_amdgcn_rcpf(d);
        float xn2 = fmaf(s, rd * rd, EPS);
        float xn  = sqrtf(xn2);
        float inv_xnd = __builtin_amdgcn_rsqf(xn2) * rd;   // 1/(xn*d)
        float xc  = fminf(xn, 1.0f - 1e-5f);
        float wc  = w * (fast_atanh(xc) * inv_xnd);
#pragma unroll
        for (int m = 0; m < M_; ++m) g[m] = fmaf(wc, y[m], g[m]);
    }

    // ---- reduce: lanes (k, k+32) within each wave, then 8 waves via LDS ----
#pragma unroll
    for (int m = 0; m < M_; ++m) g[m] += __shfl_down(g[m], 32, 64);
    if (lane < K_) {
#pragma unroll
        for (int m = 0; m < M_; ++m) red[wv][lane * (M_ + 1) + m] = g[m];
    }
    __syncthreads();

    // ---- publish slice: 256 packed u64 atomic exchanges (threads 0..255) ----
    unsigned long long* dst = G_part + ((size_t)b * NCHUNK + c) * SLICE64;
    if (tid < SLICE64) {
        int p  = tid;
        int kk = p >> 3, mp = (p & 7) * 2;
        int i0 = kk * (M_ + 1) + mp;
        float v0 = 0.0f, v1 = 0.0f;
#pragma unroll
        for (int w = 0; w < NWAVE; ++w) { v0 += red[w][i0]; v1 += red[w][i0 + 1]; }
        unsigned long long pk =
            ((unsigned long long)__float_as_uint(v1) << 32) | __float_as_uint(v0);
        __hip_atomic_exchange(dst + p, pk, __ATOMIC_RELAXED,
                              __HIP_MEMORY_SCOPE_AGENT);
    }
    asm volatile("s_waitcnt vmcnt(0)" ::: "memory");   // slice performed
    __syncthreads();

    // ---- publish done flag (after all slice exchanges ack'd) ----
    if (tid == 0) {
        __hip_atomic_exchange(&done[b * NCHUNK + c],
                              (FLAG_TAG << 16) | (unsigned)local_mn,
                              __ATOMIC_RELAXED, __HIP_MEMORY_SCOPE_AGENT);
        asm volatile("s_waitcnt vmcnt(0)" ::: "memory");  // flag ack'd
    }
    __syncthreads();

    // ---- read the batch's 4 done flags ONCE (no spinning) ----
    if (tid < NCHUNK)
        fl_lds[tid] = __hip_atomic_fetch_add(&done[b * NCHUNK + tid], 0u,
                                             __ATOMIC_RELAXED,
                                             __HIP_MEMORY_SCOPE_AGENT);
    __syncthreads();

    bool allset = true;
#pragma unroll
    for (int cc = 0; cc < NCHUNK; ++cc) {
        unsigned v = fl_lds[cc];
        if ((v >> 16) != FLAG_TAG || (v & 0xFFFFu) > (unsigned)NC) allset = false;
    }
    if (!allset) return;   // an earlier-finishing block; the last one will see all 4

    // ---- one-shot election: exactly one winner per batch ----
    if (tid == 0) {
        unsigned old = __hip_atomic_exchange(&elect[b], (FLAG_TAG << 16) | 1u,
                                             __ATOMIC_RELAXED,
                                             __HIP_MEMORY_SCOPE_AGENT);
        win = ((old >> 16) != FLAG_TAG);   // poison/first -> win; TAG -> already won
    }
    __syncthreads();
    if (!win) return;

    // ---- winner: epilogue for batch b ----
    int ninc = NCHUNK;
#pragma unroll
    for (int cc = 0; cc < NCHUNK; ++cc) {
        if ((fl_lds[cc] & 0xFFFFu) < (unsigned)NC) { ninc = cc + 1; break; }
    }

    unsigned long long* Gb = G_part + (size_t)b * NCHUNK * SLICE64;
    if (tid < SLICE64) {
        int p  = tid;
        float s0 = 0.0f, s1 = 0.0f;
        for (int cc = 0; cc < ninc; ++cc) {
            unsigned long long pk = __hip_atomic_fetch_add(
                &Gb[cc * SLICE64 + p], 0ULL,
                __ATOMIC_RELAXED, __HIP_MEMORY_SCOPE_AGENT);
            s0 += __uint_as_float((unsigned)pk);
            s1 += __uint_as_float((unsigned)(pk >> 32));
        }
        int kk = p >> 3, mp = (p & 7) * 2;
        S_lds[kk * M_ + mp]     = s0;
        S_lds[kk * M_ + mp + 1] = s1;
    }
    __syncthreads();

    if (tid < K_) {   // wave 0, lanes 0..31; lane = k
        const int klane = tid;
        float S[M_];
#pragma unroll
        for (int m = 0; m < M_; ++m)
            S[m] = theta[klane * M_ + m] * S_lds[klane * M_ + m];

        // inclusive prefix sum over k within the 32-lane segment
#pragma unroll
        for (int m = 0; m < M_; ++m) {
            float v = S[m];
#pragma unroll
            for (int off = 1; off < K_; off <<= 1) {
                float up = __shfl_up(v, off, 32);
                if (klane >= off) v += up;
            }
            S[m] = v;
        }

        float sn2 = 0.0f;
#pragma unroll
        for (int m = 0; m < M_; ++m) sn2 = fmaf(S[m], S[m], sn2);
        float Sn = sqrtf(sn2 + EPS);
        float e2 = __expf(-2.0f * Sn);
        float r  = (1.0f - e2) * __builtin_amdgcn_rcpf((1.0f + e2) * Sn);

        float xd[M_];
        float xdn2 = 0.0f;
#pragma unroll
        for (int m = 0; m < M_; ++m) { xd[m] = r * S[m]; xdn2 = fmaf(xd[m], xd[m], xdn2); }
        float scale = 2.0f / fmaxf(1.0f - xdn2, 1e-7f);

#pragma unroll
        for (int m = 0; m < M_; ++m)
            out[(size_t)b * (K_ * M_) + klane * M_ + m] = scale * xd[m];
    }
}

extern "C" void kernel_launch(void* const* d_in, const int* in_sizes, int n_in,
                              void* d_out, int out_size, void* d_ws, size_t ws_size,
                              hipStream_t stream) {
    const float* dgm     = (const float*)d_in[0];   // (B, N, 17)
    const float* theta   = (const float*)d_in[1];   // (K, M)
    const float* class_w = (const float*)d_in[2];   // (2,)
    float* out = (float*)d_out;                     // (B, K*M) f32

    // ws layout: G_part [B][NCHUNK][256] u64 (256 KiB), done [B*NCHUNK] u32,
    // elect [B] u32. All cross-block traffic is device-scope atomics; TAG
    // discipline handles the per-iteration ws poison (validated R3-R5).
    unsigned long long* G_part = (unsigned long long*)d_ws;
    unsigned* done  = (unsigned*)((char*)d_ws +
                      (size_t)B_ * NCHUNK * SLICE64 * sizeof(unsigned long long));
    unsigned* elect = done + B_ * NCHUNK;

    dim3 grid(NCHUNK, B_);   // 128 blocks; no co-residency or ordering assumptions
    pml_fused_kernel<<<grid, THREADS, 0, stream>>>(dgm, theta, class_w,
                                                   G_part, done, elect, out);
}